// Round 6
// baseline (134.871 us; speedup 1.0000x reference)
//
#include <hip/hip_runtime.h>
#include <hip/hip_bf16.h>

#define B_DIM 4
#define C_DIM 256
#define N_DIM 4096

typedef unsigned short ushort8 __attribute__((ext_vector_type(8)));
typedef unsigned short ushort4v __attribute__((ext_vector_type(4)));
typedef short          short8  __attribute__((ext_vector_type(8)));
typedef float          f32x4   __attribute__((ext_vector_type(4)));

__device__ __forceinline__ unsigned short f2bf(float x) {
    __hip_bfloat16 h = __float2bfloat16(x);
    return __builtin_bit_cast(unsigned short, h);
}
__device__ __forceinline__ float b2f(unsigned short u) {
    return __builtin_bit_cast(float, (unsigned)u << 16);
}
__device__ __forceinline__ short8 pk8(float4 a, float4 b) {
    short8 r;
    r[0] = (short)f2bf(a.x); r[1] = (short)f2bf(a.y);
    r[2] = (short)f2bf(a.z); r[3] = (short)f2bf(a.w);
    r[4] = (short)f2bf(b.x); r[5] = (short)f2bf(b.y);
    r[6] = (short)f2bf(b.z); r[7] = (short)f2bf(b.w);
    return r;
}

// ---------------------------------------------------------------------------
// castX: X fp32 [b][c][n] -> XT bf16 [b][n][c]  (B-operand wants c contiguous)
// Both global sides fully coalesced; transpose through padded LDS.
// ---------------------------------------------------------------------------
__global__ __launch_bounds__(256) void castX(
    const float* __restrict__ X, unsigned short* __restrict__ XT)
{
    __shared__ float tile[64][65];
    const int n0 = blockIdx.x * 64, c0 = blockIdx.y * 64, b = blockIdx.z;
    const int tid = threadIdx.x;
    {
        int c = tid >> 2, ns = (tid & 3) * 16;
        const float* src = X + ((size_t)(b * C_DIM + c0 + c)) * N_DIM + n0 + ns;
        #pragma unroll
        for (int j = 0; j < 4; ++j) {
            float4 f = *(const float4*)(src + j * 4);
            tile[c][ns + j * 4 + 0] = f.x; tile[c][ns + j * 4 + 1] = f.y;
            tile[c][ns + j * 4 + 2] = f.z; tile[c][ns + j * 4 + 3] = f.w;
        }
    }
    __syncthreads();
    {
        int n = tid >> 2, cs = (tid & 3) * 16;
        ushort8 u0, u1;
        #pragma unroll
        for (int j = 0; j < 8; ++j) u0[j] = f2bf(tile[cs + j][n]);
        #pragma unroll
        for (int j = 0; j < 8; ++j) u1[j] = f2bf(tile[cs + 8 + j][n]);
        unsigned short* dst = XT + ((size_t)b * N_DIM + n0 + n) * C_DIM + c0 + cs;
        *(ushort8*)dst       = u0;
        *(ushort8*)(dst + 8) = u1;
    }
}

// ---------------------------------------------------------------------------
// gemm_kv: fused k+v GEMM via bf16 MFMA 16x16x32.  No main-loop LDS/barriers.
// Block 256 thr = 4 waves; tile 64r x 128n, BOTH mats.  Wave = 32r x 64n.
// A-frags: W fp32 rows read directly (2x float4) + in-reg cvt (no castW;
//          W is 512KB, L2-resident, reused by 32 n-blocks).
// B-frags: XT bf16 rows as single 16B ushort8 loads (1KB/wave-instr).
// k unscaled: 1/sqrt(256) folded into scores' H load.
// Epilogue: LDS transpose -> 16B coalesced ushort8 global stores.
// ---------------------------------------------------------------------------
__global__ __launch_bounds__(256, 2) void gemm_kv(
    const unsigned short* __restrict__ XT,
    const float* __restrict__ Wk,
    const float* __restrict__ Wv,
    unsigned short* __restrict__ Kout,
    unsigned short* __restrict__ Vout)
{
    __shared__ unsigned short sOut[64][136];

    const int b  = blockIdx.z;
    const int r0 = blockIdx.y * 64;
    const int n0 = blockIdx.x * 128;
    const int tid = threadIdx.x, lane = tid & 63, wid = tid >> 6;
    const int ln = lane & 15, q = lane >> 4;
    const int cw = wid & 1, rw = wid >> 1;
    const int rbase = r0 + rw * 32;
    const int nbase = n0 + cw * 64;

    const unsigned short* XTb = XT + (size_t)b * N_DIM * C_DIM;

    const float* pk0 = Wk + (size_t)(rbase + ln) * C_DIM;
    const float* pk1 = pk0 + 16 * C_DIM;
    const float* pv0 = Wv + (size_t)(rbase + ln) * C_DIM;
    const float* pv1 = pv0 + 16 * C_DIM;
    const unsigned short* pb0 = XTb + (size_t)(nbase + ln) * C_DIM + q * 8;
    const unsigned short* pb1 = pb0 + 16 * C_DIM;
    const unsigned short* pb2 = pb0 + 32 * C_DIM;
    const unsigned short* pb3 = pb0 + 48 * C_DIM;

    f32x4 ak[2][4] = {};
    f32x4 av[2][4] = {};

    #pragma unroll
    for (int c0 = 0; c0 < C_DIM; c0 += 32) {
        const int cq = c0 + q * 8;
        short8 A0 = pk8(*(const float4*)(pk0 + cq), *(const float4*)(pk0 + cq + 4));
        short8 A1 = pk8(*(const float4*)(pk1 + cq), *(const float4*)(pk1 + cq + 4));
        short8 V0 = pk8(*(const float4*)(pv0 + cq), *(const float4*)(pv0 + cq + 4));
        short8 V1 = pk8(*(const float4*)(pv1 + cq), *(const float4*)(pv1 + cq + 4));
        short8 Bf[4];
        Bf[0] = *(const short8*)(pb0 + c0);
        Bf[1] = *(const short8*)(pb1 + c0);
        Bf[2] = *(const short8*)(pb2 + c0);
        Bf[3] = *(const short8*)(pb3 + c0);
        #pragma unroll
        for (int j = 0; j < 4; ++j) {
            ak[0][j] = __builtin_amdgcn_mfma_f32_16x16x32_bf16(A0, Bf[j], ak[0][j], 0, 0, 0);
            ak[1][j] = __builtin_amdgcn_mfma_f32_16x16x32_bf16(A1, Bf[j], ak[1][j], 0, 0, 0);
            av[0][j] = __builtin_amdgcn_mfma_f32_16x16x32_bf16(V0, Bf[j], av[0][j], 0, 0, 0);
            av[1][j] = __builtin_amdgcn_mfma_f32_16x16x32_bf16(V1, Bf[j], av[1][j], 0, 0, 0);
        }
    }

    // ---- epilogue: LDS transpose -> coalesced 16B stores ----
    const int rl  = tid >> 2;             // 0..63 readback row
    const int csh = (tid & 3) * 8;        // ushort col offset
    unsigned short* Kb = Kout + (size_t)b * C_DIM * N_DIM + (size_t)(r0 + rl) * N_DIM + n0;
    unsigned short* Vb = Vout + (size_t)b * C_DIM * N_DIM + (size_t)(r0 + rl) * N_DIM + n0;

    #pragma unroll
    for (int i = 0; i < 2; ++i)
        #pragma unroll
        for (int reg = 0; reg < 4; ++reg) {
            int rr = rw * 32 + i * 16 + q * 4 + reg;
            #pragma unroll
            for (int j = 0; j < 4; ++j)
                sOut[rr][cw * 64 + ln + j * 16] = f2bf(ak[i][j][reg]);
        }
    __syncthreads();
    #pragma unroll
    for (int j = 0; j < 4; ++j)
        *(ushort8*)(Kb + csh + j * 32) = *(const ushort8*)&sOut[rl][csh + j * 32];
    __syncthreads();

    #pragma unroll
    for (int i = 0; i < 2; ++i)
        #pragma unroll
        for (int reg = 0; reg < 4; ++reg) {
            int rr = rw * 32 + i * 16 + q * 4 + reg;
            #pragma unroll
            for (int j = 0; j < 4; ++j)
                sOut[rr][cw * 64 + ln + j * 16] = f2bf(av[i][j][reg]);
        }
    __syncthreads();
    #pragma unroll
    for (int j = 0; j < 4; ++j)
        *(ushort8*)(Vb + csh + j * 32) = *(const ushort8*)&sOut[rl][csh + j * 32];
}

// ---------------------------------------------------------------------------
// scores: s[b,n,dd] = sum_r (H[b,r,n]*scale) * k[b,r,n+dd-2]   (k bf16)
// Block = 512 thr = 32 n x 16 r-chunks, direct global loads, LDS tree-reduce.
// Emits EWT[b][ddp][m] (band weights indexed by OUTPUT column m) and
// Wout[b][n] = 1/denom.   EWT[4-dd][n+dd-2] = (exp(s[n,dd])-1)/denom[n]
// ---------------------------------------------------------------------------
__global__ __launch_bounds__(512) void scores(
    const float* __restrict__ H,
    const unsigned short* __restrict__ K,
    float* __restrict__ EWT,
    float* __restrict__ Wout)
{
    __shared__ float sacc[16][5][32];
    __shared__ float se[5][32];
    __shared__ float sw[32];

    const int b   = blockIdx.y;
    const int n0  = blockIdx.x * 32;
    const int tid = threadIdx.x;
    const int nl  = tid & 31;
    const int ch  = tid >> 5;          // 0..15 (r-chunk)
    const int n   = n0 + nl;

    const float* Hb = H + ((size_t)b * C_DIM + ch * 16) * N_DIM + n;
    const unsigned short* Kb = K + ((size_t)b * C_DIM + ch * 16) * N_DIM;

    int m[5];
    #pragma unroll
    for (int dd = 0; dd < 5; ++dd) {
        int mm = n + dd - 2;
        m[dd] = mm < 0 ? 0 : (mm >= N_DIM ? N_DIM - 1 : mm);
    }

    float acc[5] = {0.f, 0.f, 0.f, 0.f, 0.f};
    #pragma unroll 8
    for (int r = 0; r < 16; ++r) {
        float hv = Hb[(size_t)r * N_DIM] * 0.0625f;   // 1/sqrt(256) folded here
        const unsigned short* kr = Kb + (size_t)r * N_DIM;
        #pragma unroll
        for (int dd = 0; dd < 5; ++dd)
            acc[dd] = fmaf(hv, b2f(kr[m[dd]]), acc[dd]);
    }
    #pragma unroll
    for (int dd = 0; dd < 5; ++dd) sacc[ch][dd][nl] = acc[dd];
    __syncthreads();

    if (tid < 160) {
        const int dd = tid >> 5, nn = tid & 31;
        float s = 0.f;
        #pragma unroll
        for (int c = 0; c < 16; ++c) s += sacc[c][dd][nn];
        const int mm = n0 + nn + dd - 2;
        se[dd][nn] = (mm >= 0 && mm < N_DIM) ? expf(s) - 1.0f : 0.f;
    }
    __syncthreads();
    if (tid < 32) {
        float denom = (float)N_DIM + se[0][tid] + se[1][tid] + se[2][tid]
                                   + se[3][tid] + se[4][tid];
        float wv = 1.0f / denom;
        sw[tid] = wv;
        Wout[(size_t)b * N_DIM + n0 + tid] = wv;
    }
    __syncthreads();
    if (tid < 160) {
        const int dd = tid >> 5, nn = tid & 31;
        const int mm = n0 + nn + dd - 2;                 // output column
        if (mm >= 0 && mm < N_DIM)
            EWT[((size_t)b * 5 + (4 - dd)) * N_DIM + mm] = se[dd][nn] * sw[nn];
    }
}

// ---------------------------------------------------------------------------
// epi: fused colsum + epilogue, fully vectorized.  One block per (b,c) row.
//  S = sum_n v[n]*w[n]  (v staged into zero-padded LDS while reducing), then
//  out[m] = x[m] + S + sum_{dd=0..4} v[m+dd-2] * EWT[b][dd][m]
// ---------------------------------------------------------------------------
__global__ __launch_bounds__(256) void epi(
    const float* __restrict__ X,
    const unsigned short* __restrict__ V,
    const float* __restrict__ EWT,
    const float* __restrict__ Wn,
    float* __restrict__ Out)
{
    __shared__ unsigned short sv[N_DIM + 8];   // [0..3]=0, v at +4, tail 0
    __shared__ float sred[4];

    const int c = blockIdx.x, b = blockIdx.y;
    const int tid = threadIdx.x, lane = tid & 63, wid = tid >> 6;
    const size_t row = (size_t)b * C_DIM + c;

    if (tid < 4) { sv[tid] = 0; sv[N_DIM + 4 + tid] = 0; }

    const ushort8* v8   = (const ushort8*)(V + row * N_DIM);
    const float*   wrow = Wn + (size_t)b * N_DIM;

    float acc = 0.f;
    #pragma unroll
    for (int it = 0; it < 2; ++it) {
        int i = tid + it * 256;                 // chunk of 8
        ushort8 u = v8[i];
        *(ushort4v*)&sv[4 + i * 8]     = ushort4v{u[0], u[1], u[2], u[3]};
        *(ushort4v*)&sv[4 + i * 8 + 4] = ushort4v{u[4], u[5], u[6], u[7]};
        const float4 w0 = *(const float4*)(wrow + i * 8);
        const float4 w1 = *(const float4*)(wrow + i * 8 + 4);
        acc += b2f(u[0]) * w0.x + b2f(u[1]) * w0.y
             + b2f(u[2]) * w0.z + b2f(u[3]) * w0.w
             + b2f(u[4]) * w1.x + b2f(u[5]) * w1.y
             + b2f(u[6]) * w1.z + b2f(u[7]) * w1.w;
    }
    #pragma unroll
    for (int off = 32; off > 0; off >>= 1)
        acc += __shfl_down(acc, off, 64);
    if (lane == 0) sred[wid] = acc;
    __syncthreads();
    const float S = sred[0] + sred[1] + sred[2] + sred[3];

    const float* xrow = X + row * N_DIM;
    float*       orow = Out + row * N_DIM;
    const float* ewt  = EWT + (size_t)b * 5 * N_DIM;
    const unsigned int* svw = (const unsigned int*)sv;

    #pragma unroll
    for (int it = 0; it < 4; ++it) {
        const int g  = it * 256 + tid;          // float4 index
        const int m0 = g * 4;
        const float4 x = *(const float4*)(xrow + m0);
        unsigned int u0 = svw[2 * g + 1];
        unsigned int u1 = svw[2 * g + 2];
        unsigned int u2 = svw[2 * g + 3];
        unsigned int u3 = svw[2 * g + 4];
        float w8[8];
        w8[0] = b2f(u0 & 0xffff); w8[1] = b2f(u0 >> 16);
        w8[2] = b2f(u1 & 0xffff); w8[3] = b2f(u1 >> 16);
        w8[4] = b2f(u2 & 0xffff); w8[5] = b2f(u2 >> 16);
        w8[6] = b2f(u3 & 0xffff); w8[7] = b2f(u3 >> 16);
        const float4 t0 = *(const float4*)(ewt + 0 * N_DIM + m0);
        const float4 t1 = *(const float4*)(ewt + 1 * N_DIM + m0);
        const float4 t2 = *(const float4*)(ewt + 2 * N_DIM + m0);
        const float4 t3 = *(const float4*)(ewt + 3 * N_DIM + m0);
        const float4 t4 = *(const float4*)(ewt + 4 * N_DIM + m0);
        float4 r;
        r.x = x.x + S + w8[0]*t0.x + w8[1]*t1.x + w8[2]*t2.x + w8[3]*t3.x + w8[4]*t4.x;
        r.y = x.y + S + w8[1]*t0.y + w8[2]*t1.y + w8[3]*t2.y + w8[4]*t3.y + w8[5]*t4.y;
        r.z = x.z + S + w8[2]*t0.z + w8[3]*t1.z + w8[4]*t2.z + w8[5]*t3.z + w8[6]*t4.z;
        r.w = x.w + S + w8[3]*t0.w + w8[4]*t1.w + w8[5]*t2.w + w8[6]*t3.w + w8[7]*t4.w;
        *(float4*)(orow + m0) = r;
    }
}

// ---------------------------------------------------------------------------
extern "C" void kernel_launch(void* const* d_in, const int* in_sizes, int n_in,
                              void* d_out, int out_size, void* d_ws, size_t ws_size,
                              hipStream_t stream)
{
    const float* X  = (const float*)d_in[0];   // [B,C,N]
    const float* H  = (const float*)d_in[1];   // [B,R,N]
    const float* Wk = (const float*)d_in[2];   // [R,C]
    const float* Wv = (const float*)d_in[3];   // [C,C]
    float* out = (float*)d_out;

    const size_t TENS = (size_t)B_DIM * C_DIM * N_DIM;   // 4194304
    unsigned short* XT = (unsigned short*)d_ws;          // bf16 [b][n][c]
    unsigned short* Kb = XT + TENS;                      // bf16 [b][r][n]
    unsigned short* Vb = Kb + TENS;
    float* EWT = (float*)(Vb + TENS);                    // [b][5][m]
    float* Wn  = EWT + (size_t)B_DIM * 5 * N_DIM;        // [b][n]

    castX<<<dim3(N_DIM / 64, C_DIM / 64, B_DIM), 256, 0, stream>>>(X, XT);
    gemm_kv<<<dim3(N_DIM / 128, C_DIM / 64, B_DIM), 256, 0, stream>>>(
        XT, Wk, Wv, Kb, Vb);
    scores<<<dim3(N_DIM / 32, B_DIM),            512, 0, stream>>>(H, Kb, EWT, Wn);
    epi<<<dim3(C_DIM, B_DIM),                    256, 0, stream>>>(X, Vb, EWT, Wn, out);
}

// Round 7
// 125.694 us; speedup vs baseline: 1.0730x; 1.0730x over previous
//
#include <hip/hip_runtime.h>
#include <hip/hip_bf16.h>

#define B_DIM 4
#define C_DIM 256
#define N_DIM 4096

typedef unsigned short ushort8 __attribute__((ext_vector_type(8)));
typedef unsigned short ushort4v __attribute__((ext_vector_type(4)));
typedef short          short8  __attribute__((ext_vector_type(8)));
typedef float          f32x4   __attribute__((ext_vector_type(4)));

__device__ __forceinline__ unsigned short f2bf(float x) {
    __hip_bfloat16 h = __float2bfloat16(x);
    return __builtin_bit_cast(unsigned short, h);
}
__device__ __forceinline__ float b2f(unsigned short u) {
    return __builtin_bit_cast(float, (unsigned)u << 16);
}

// ---------------------------------------------------------------------------
// castXW: one launch does both precasts.
//  z = 0..3 : X fp32 [b][c][n] -> XT bf16 [b][n][c]  (64x64 LDS transpose)
//  z = 4    : W fp32 [r][c] -> bf16 [r][c]; 1/sqrt(256) folded into Wk.
// ---------------------------------------------------------------------------
__global__ __launch_bounds__(256) void castXW(
    const float* __restrict__ X, unsigned short* __restrict__ XT,
    const float* __restrict__ Wk, const float* __restrict__ Wv,
    unsigned short* __restrict__ Wkb, unsigned short* __restrict__ Wvb)
{
    __shared__ float tile[64][65];
    const int tid = threadIdx.x;
    const int b = blockIdx.z;

    if (b == 4) {                       // ---- W cast slice ----
        const int bid = blockIdx.y * 64 + blockIdx.x;
        if (bid >= 64) return;
        const int mat = bid >> 5;       // 0: Wk, 1: Wv
        const float* src = mat ? Wv : Wk;
        unsigned short* dst = mat ? Wvb : Wkb;
        const float scale = mat ? 1.0f : 0.0625f;
        int idx = (bid & 31) * 2048 + tid * 8;
        float4 f0 = *(const float4*)(src + idx);
        float4 f1 = *(const float4*)(src + idx + 4);
        ushort8 u;
        u[0] = f2bf(f0.x * scale); u[1] = f2bf(f0.y * scale);
        u[2] = f2bf(f0.z * scale); u[3] = f2bf(f0.w * scale);
        u[4] = f2bf(f1.x * scale); u[5] = f2bf(f1.y * scale);
        u[6] = f2bf(f1.z * scale); u[7] = f2bf(f1.w * scale);
        *(ushort8*)(dst + idx) = u;
        return;
    }

    // ---- X transpose-cast slice ----
    const int n0 = blockIdx.x * 64, c0 = blockIdx.y * 64;
    {
        int c = tid >> 2, ns = (tid & 3) * 16;
        const float* src = X + ((size_t)(b * C_DIM + c0 + c)) * N_DIM + n0 + ns;
        #pragma unroll
        for (int j = 0; j < 4; ++j) {
            float4 f = *(const float4*)(src + j * 4);
            tile[c][ns + j * 4 + 0] = f.x; tile[c][ns + j * 4 + 1] = f.y;
            tile[c][ns + j * 4 + 2] = f.z; tile[c][ns + j * 4 + 3] = f.w;
        }
    }
    __syncthreads();
    {
        int n = tid >> 2, cs = (tid & 3) * 16;
        ushort8 u0, u1;
        #pragma unroll
        for (int j = 0; j < 8; ++j) u0[j] = f2bf(tile[cs + j][n]);
        #pragma unroll
        for (int j = 0; j < 8; ++j) u1[j] = f2bf(tile[cs + 8 + j][n]);
        unsigned short* dst = XT + ((size_t)b * N_DIM + n0 + n) * C_DIM + c0 + cs;
        *(ushort8*)dst       = u0;
        *(ushort8*)(dst + 8) = u1;
    }
}

// ---------------------------------------------------------------------------
// gemm_kv: LDS-free fused k+v GEMM via bf16 MFMA 16x16x32.  (R4-proven form)
// Block = 256 thr = 4 waves; tile 128n x 64r, BOTH mats.  Wave = 64n x 32r.
// A-frags (W rows, k-contig) and B-frags (XT rows, k-contig) loaded as
// 16B global loads straight into MFMA fragments.  No LDS, no barriers.
// ---------------------------------------------------------------------------
__global__ __launch_bounds__(256) void gemm_kv(
    const unsigned short* __restrict__ XT,
    const unsigned short* __restrict__ Wkb,
    const unsigned short* __restrict__ Wvb,
    unsigned short* __restrict__ Kout,
    unsigned short* __restrict__ Vout)
{
    const int b  = blockIdx.z;
    const int r0 = blockIdx.y * 64;
    const int n0 = blockIdx.x * 128;
    const int tid = threadIdx.x, lane = tid & 63, wid = tid >> 6;
    const int ln = lane & 15, q = lane >> 4;
    const int cw = wid & 1, rw = wid >> 1;
    const int rbase = r0 + rw * 32;
    const int nbase = n0 + cw * 64;

    const unsigned short* XTb = XT + (size_t)b * N_DIM * C_DIM;

    const unsigned short* pa0 = Wkb + (size_t)(rbase + ln) * C_DIM + q * 8;
    const unsigned short* pa1 = pa0 + 16 * C_DIM;
    const unsigned short* pv0 = Wvb + (size_t)(rbase + ln) * C_DIM + q * 8;
    const unsigned short* pv1 = pv0 + 16 * C_DIM;
    const unsigned short* pb0 = XTb + (size_t)(nbase + ln) * C_DIM + q * 8;
    const unsigned short* pb1 = pb0 + 16 * C_DIM;
    const unsigned short* pb2 = pb0 + 32 * C_DIM;
    const unsigned short* pb3 = pb0 + 48 * C_DIM;

    f32x4 ak[2][4] = {};
    f32x4 av[2][4] = {};

    #pragma unroll
    for (int c0 = 0; c0 < C_DIM; c0 += 32) {
        short8 A0 = *(const short8*)(pa0 + c0);
        short8 A1 = *(const short8*)(pa1 + c0);
        short8 V0 = *(const short8*)(pv0 + c0);
        short8 V1 = *(const short8*)(pv1 + c0);
        short8 Bf[4];
        Bf[0] = *(const short8*)(pb0 + c0);
        Bf[1] = *(const short8*)(pb1 + c0);
        Bf[2] = *(const short8*)(pb2 + c0);
        Bf[3] = *(const short8*)(pb3 + c0);
        #pragma unroll
        for (int j = 0; j < 4; ++j) {
            ak[0][j] = __builtin_amdgcn_mfma_f32_16x16x32_bf16(A0, Bf[j], ak[0][j], 0, 0, 0);
            ak[1][j] = __builtin_amdgcn_mfma_f32_16x16x32_bf16(A1, Bf[j], ak[1][j], 0, 0, 0);
            av[0][j] = __builtin_amdgcn_mfma_f32_16x16x32_bf16(V0, Bf[j], av[0][j], 0, 0, 0);
            av[1][j] = __builtin_amdgcn_mfma_f32_16x16x32_bf16(V1, Bf[j], av[1][j], 0, 0, 0);
        }
    }

    unsigned short* Kb = Kout + (size_t)b * C_DIM * N_DIM;
    unsigned short* Vb = Vout + (size_t)b * C_DIM * N_DIM;
    #pragma unroll
    for (int i = 0; i < 2; ++i)
        #pragma unroll
        for (int reg = 0; reg < 4; ++reg) {
            int r = rbase + i * 16 + q * 4 + reg;
            size_t base = (size_t)r * N_DIM + nbase + ln;
            #pragma unroll
            for (int j = 0; j < 4; ++j) {
                Kb[base + j * 16] = f2bf(ak[i][j][reg]);
                Vb[base + j * 16] = f2bf(av[i][j][reg]);
            }
        }
}

// ---------------------------------------------------------------------------
// scores: s[b,n,dd] = sum_r H[b,r,n] * k[b,r,n+dd-2]   (k pre-scaled, bf16)
// Block = 512 thr = 32 n x 16 r-chunks, direct global loads, LDS tree-reduce.
// Emits EWT[b][ddp][m] (band weights indexed by OUTPUT column m) and
// Wout[b][n] = 1/denom.   EWT[4-dd][n+dd-2] = (exp(s[n,dd])-1)/denom[n]
// ---------------------------------------------------------------------------
__global__ __launch_bounds__(512) void scores(
    const float* __restrict__ H,
    const unsigned short* __restrict__ K,
    float* __restrict__ EWT,
    float* __restrict__ Wout)
{
    __shared__ float sacc[16][5][32];
    __shared__ float se[5][32];
    __shared__ float sw[32];

    const int b   = blockIdx.y;
    const int n0  = blockIdx.x * 32;
    const int tid = threadIdx.x;
    const int nl  = tid & 31;
    const int ch  = tid >> 5;          // 0..15 (r-chunk)
    const int n   = n0 + nl;

    const float* Hb = H + ((size_t)b * C_DIM + ch * 16) * N_DIM + n;
    const unsigned short* Kb = K + ((size_t)b * C_DIM + ch * 16) * N_DIM;

    int m[5];
    #pragma unroll
    for (int dd = 0; dd < 5; ++dd) {
        int mm = n + dd - 2;
        m[dd] = mm < 0 ? 0 : (mm >= N_DIM ? N_DIM - 1 : mm);
    }

    float acc[5] = {0.f, 0.f, 0.f, 0.f, 0.f};
    #pragma unroll 8
    for (int r = 0; r < 16; ++r) {
        float hv = Hb[(size_t)r * N_DIM];
        const unsigned short* kr = Kb + (size_t)r * N_DIM;
        #pragma unroll
        for (int dd = 0; dd < 5; ++dd)
            acc[dd] = fmaf(hv, b2f(kr[m[dd]]), acc[dd]);
    }
    #pragma unroll
    for (int dd = 0; dd < 5; ++dd) sacc[ch][dd][nl] = acc[dd];
    __syncthreads();

    if (tid < 160) {
        const int dd = tid >> 5, nn = tid & 31;
        float s = 0.f;
        #pragma unroll
        for (int c = 0; c < 16; ++c) s += sacc[c][dd][nn];
        const int mm = n0 + nn + dd - 2;
        se[dd][nn] = (mm >= 0 && mm < N_DIM) ? expf(s) - 1.0f : 0.f;
    }
    __syncthreads();
    if (tid < 32) {
        float denom = (float)N_DIM + se[0][tid] + se[1][tid] + se[2][tid]
                                   + se[3][tid] + se[4][tid];
        float wv = 1.0f / denom;
        sw[tid] = wv;
        Wout[(size_t)b * N_DIM + n0 + tid] = wv;
    }
    __syncthreads();
    if (tid < 160) {
        const int dd = tid >> 5, nn = tid & 31;
        const int mm = n0 + nn + dd - 2;                 // output column
        if (mm >= 0 && mm < N_DIM)
            EWT[((size_t)b * 5 + (4 - dd)) * N_DIM + mm] = se[dd][nn] * sw[nn];
    }
}

// ---------------------------------------------------------------------------
// epi: fused colsum + epilogue, fully vectorized.  One block per (b,c) row.
//  S = sum_n v[n]*w[n]  (v staged into zero-padded LDS while reducing), then
//  out[m] = x[m] + S + sum_{dd=0..4} v[m+dd-2] * EWT[b][dd][m]
// ---------------------------------------------------------------------------
__global__ __launch_bounds__(256) void epi(
    const float* __restrict__ X,
    const unsigned short* __restrict__ V,
    const float* __restrict__ EWT,
    const float* __restrict__ Wn,
    float* __restrict__ Out)
{
    __shared__ unsigned short sv[N_DIM + 8];   // [0..3]=0, v at +4, tail 0
    __shared__ float sred[4];

    const int c = blockIdx.x, b = blockIdx.y;
    const int tid = threadIdx.x, lane = tid & 63, wid = tid >> 6;
    const size_t row = (size_t)b * C_DIM + c;

    if (tid < 4) { sv[tid] = 0; sv[N_DIM + 4 + tid] = 0; }

    const ushort8* v8   = (const ushort8*)(V + row * N_DIM);
    const float*   wrow = Wn + (size_t)b * N_DIM;

    float acc = 0.f;
    #pragma unroll
    for (int it = 0; it < 2; ++it) {
        int i = tid + it * 256;                 // chunk of 8
        ushort8 u = v8[i];
        *(ushort4v*)&sv[4 + i * 8]     = ushort4v{u[0], u[1], u[2], u[3]};
        *(ushort4v*)&sv[4 + i * 8 + 4] = ushort4v{u[4], u[5], u[6], u[7]};
        const float4 w0 = *(const float4*)(wrow + i * 8);
        const float4 w1 = *(const float4*)(wrow + i * 8 + 4);
        acc += b2f(u[0]) * w0.x + b2f(u[1]) * w0.y
             + b2f(u[2]) * w0.z + b2f(u[3]) * w0.w
             + b2f(u[4]) * w1.x + b2f(u[5]) * w1.y
             + b2f(u[6]) * w1.z + b2f(u[7]) * w1.w;
    }
    #pragma unroll
    for (int off = 32; off > 0; off >>= 1)
        acc += __shfl_down(acc, off, 64);
    if (lane == 0) sred[wid] = acc;
    __syncthreads();
    const float S = sred[0] + sred[1] + sred[2] + sred[3];

    const float* xrow = X + row * N_DIM;
    float*       orow = Out + row * N_DIM;
    const float* ewt  = EWT + (size_t)b * 5 * N_DIM;
    const unsigned int* svw = (const unsigned int*)sv;

    #pragma unroll
    for (int it = 0; it < 4; ++it) {
        const int g  = it * 256 + tid;          // float4 index
        const int m0 = g * 4;
        const float4 x = *(const float4*)(xrow + m0);
        unsigned int u0 = svw[2 * g + 1];
        unsigned int u1 = svw[2 * g + 2];
        unsigned int u2 = svw[2 * g + 3];
        unsigned int u3 = svw[2 * g + 4];
        float w8[8];
        w8[0] = b2f(u0 & 0xffff); w8[1] = b2f(u0 >> 16);
        w8[2] = b2f(u1 & 0xffff); w8[3] = b2f(u1 >> 16);
        w8[4] = b2f(u2 & 0xffff); w8[5] = b2f(u2 >> 16);
        w8[6] = b2f(u3 & 0xffff); w8[7] = b2f(u3 >> 16);
        const float4 t0 = *(const float4*)(ewt + 0 * N_DIM + m0);
        const float4 t1 = *(const float4*)(ewt + 1 * N_DIM + m0);
        const float4 t2 = *(const float4*)(ewt + 2 * N_DIM + m0);
        const float4 t3 = *(const float4*)(ewt + 3 * N_DIM + m0);
        const float4 t4 = *(const float4*)(ewt + 4 * N_DIM + m0);
        float4 r;
        r.x = x.x + S + w8[0]*t0.x + w8[1]*t1.x + w8[2]*t2.x + w8[3]*t3.x + w8[4]*t4.x;
        r.y = x.y + S + w8[1]*t0.y + w8[2]*t1.y + w8[3]*t2.y + w8[4]*t3.y + w8[5]*t4.y;
        r.z = x.z + S + w8[2]*t0.z + w8[3]*t1.z + w8[4]*t2.z + w8[5]*t3.z + w8[6]*t4.z;
        r.w = x.w + S + w8[3]*t0.w + w8[4]*t1.w + w8[5]*t2.w + w8[6]*t3.w + w8[7]*t4.w;
        *(float4*)(orow + m0) = r;
    }
}

// ---------------------------------------------------------------------------
extern "C" void kernel_launch(void* const* d_in, const int* in_sizes, int n_in,
                              void* d_out, int out_size, void* d_ws, size_t ws_size,
                              hipStream_t stream)
{
    const float* X  = (const float*)d_in[0];   // [B,C,N]
    const float* H  = (const float*)d_in[1];   // [B,R,N]
    const float* Wk = (const float*)d_in[2];   // [R,C]
    const float* Wv = (const float*)d_in[3];   // [C,C]
    float* out = (float*)d_out;

    const size_t TENS = (size_t)B_DIM * C_DIM * N_DIM;   // 4194304
    unsigned short* XT  = (unsigned short*)d_ws;         // bf16 [b][n][c]
    unsigned short* Wkb = XT  + TENS;                    // 65536
    unsigned short* Wvb = Wkb + 65536;
    unsigned short* Kb  = Wvb + 65536;                   // bf16 [b][r][n]
    unsigned short* Vb  = Kb  + TENS;
    float* EWT = (float*)(Vb + TENS);                    // [b][5][m]
    float* Wn  = EWT + (size_t)B_DIM * 5 * N_DIM;        // [b][n]

    castXW<<<dim3(N_DIM / 64, C_DIM / 64, B_DIM + 1), 256, 0, stream>>>(
        X, XT, Wk, Wv, Wkb, Wvb);
    gemm_kv<<<dim3(N_DIM / 128, C_DIM / 64, B_DIM), 256, 0, stream>>>(
        XT, Wkb, Wvb, Kb, Vb);
    scores<<<dim3(N_DIM / 32, B_DIM),            512, 0, stream>>>(H, Kb, EWT, Wn);
    epi<<<dim3(C_DIM, B_DIM),                    256, 0, stream>>>(X, Vb, EWT, Wn, out);
}